// Round 10
// baseline (306.679 us; speedup 1.0000x reference)
//
#include <hip/hip_runtime.h>
#include <math.h>

#define NN 32768
#define NE 262144
#define CD 128
#define NH 8
#define NT 8
#define NR 8

typedef unsigned short u16;
typedef unsigned long long ull;
typedef __attribute__((ext_vector_type(8))) short bhalf8;
typedef __attribute__((ext_vector_type(4))) float f32x4;

// ---------------- workspace layout (bytes) ----------------
// WqT  @ 0         262144   bf16, MFMA-fragment order [t][ct][kk][quad][lx][8]
// WkT  @ 262144    262144   (fused rel_att)
// WvT  @ 524288    262144   (fused rel_msg)
// WaT  @ 786432    262144
// bkf  @ 1048576   4096     fp32 fused bias
// bvf  @ 1052672   4096
// exs  @ 1056768   (NE+64)*8*4  = 8390656
// vts  @ 9447424   (NE+64)*128*2 = 67125248
// deg  @ 76572672  NN*4
// dcur @ 76703744  NN*4   (adjacent: one memset covers deg+dcur)
// dbase@ 76834816  NN*4
// nperm@ 78014464  NN*4
// ectr @ 78145536  64 ints
// nctr @ 78145792  64 ints
// epart@ 78146048  1024*8 ints = 32768
// npart@ 78178816  128*8 ints  = 4096
// xb   @ 78182912  NN*CD*2 = 8388608   (bf16 x)
// epack@ 86571520  NE*16 = 4194304     (int4 {src,dst,pos,pad} per attr-slot)

__device__ __forceinline__ u16 f2b(float f) {
    union { float f; unsigned u; } v; v.f = f;
    unsigned r = v.u + 0x7FFF + ((v.u >> 16) & 1);
    return (u16)(r >> 16);
}
__device__ __forceinline__ float b2f(unsigned h) {
    union { unsigned u; float f; } v; v.u = h << 16;
    return v.f;
}

#define PREP_BLOCKS 2057
#define XB_BLOCKS 2048
#define HIST_BLOCKS 1024

// weights prep (0..2056) + x->bf16 (2057..4104) + hists (4105..5128)
// deg/dcur zeroed by hipMemsetAsync before this launch.
__global__ void prep_all(const float* __restrict__ Wk, const float* __restrict__ bk,
                         const float* __restrict__ Wq,
                         const float* __restrict__ Wv, const float* __restrict__ bv,
                         const float* __restrict__ Wa,
                         const float* __restrict__ Aatt, const float* __restrict__ Amsg,
                         const float* __restrict__ x,
                         const int* __restrict__ ea, const int* __restrict__ tidv,
                         const int* __restrict__ dstv,
                         u16* __restrict__ WqT, u16* __restrict__ WkT,
                         u16* __restrict__ WvT, u16* __restrict__ WaT,
                         float* __restrict__ bkf, float* __restrict__ bvf,
                         u16* __restrict__ xb,
                         int* __restrict__ epart, int* __restrict__ npart,
                         int* __restrict__ deg) {
    const int bx = blockIdx.x;
    if (bx >= PREP_BLOCKS + XB_BLOCKS) {
        // ---- histograms ----
        __shared__ int wc[4][8];
        const int hb = bx - PREP_BLOCKS - XB_BLOCKS;
        const int tid = threadIdx.x;
        const int lane = tid & 63, w = tid >> 6;
        int i = hb * 256 + tid;
        int t = ea[i];
        atomicAdd(&deg[dstv[i]], 1);
#pragma unroll
        for (int u = 0; u < 8; ++u) {
            ull m = __ballot(t == u);
            if (lane == 0) wc[w][u] = __popcll(m);
        }
        __syncthreads();
        if (tid < 8) epart[hb * 8 + tid] = wc[0][tid] + wc[1][tid] + wc[2][tid] + wc[3][tid];
        if (hb < NN / 256) {
            int tn = tidv[i];
            __syncthreads();
#pragma unroll
            for (int u = 0; u < 8; ++u) {
                ull m = __ballot(tn == u);
                if (lane == 0) wc[w][u] = __popcll(m);
            }
            __syncthreads();
            if (tid < 8) npart[hb * 8 + tid] = wc[0][tid] + wc[1][tid] + wc[2][tid] + wc[3][tid];
        }
        return;
    }
    if (bx >= PREP_BLOCKS) {
        int zi = (bx - PREP_BLOCKS) * 256 + threadIdx.x;
        long basei = (long)zi * 8;
        float4 v0 = *(const float4*)(x + basei);
        float4 v1 = *(const float4*)(x + basei + 4);
        bhalf8 pk;
        pk[0] = (short)f2b(v0.x); pk[1] = (short)f2b(v0.y);
        pk[2] = (short)f2b(v0.z); pk[3] = (short)f2b(v0.w);
        pk[4] = (short)f2b(v1.x); pk[5] = (short)f2b(v1.y);
        pk[6] = (short)f2b(v1.z); pk[7] = (short)f2b(v1.w);
        *(bhalf8*)(xb + basei) = pk;
        return;
    }
    const int WCNT = NT * CD * CD;  // 131072 per matrix
    int idx = bx * 256 + threadIdx.x;
    if (idx < 4 * WCNT) {
        int mat = idx >> 17;
        int o = idx & (WCNT - 1);
        int t = o >> 14;
        int n = (o >> 7) & 127;
        int k = o & 127;
        int ct = n >> 4, lx2 = n & 15, kk = k >> 5, qd = (k >> 3) & 3, dd = k & 7;
        int oo = t * 16384 + (((ct * 4 + kk) * 4 + qd) * 16 + lx2) * 8 + dd;
        if (mat == 0) {
            WqT[oo] = f2b(Wq[(t * CD + k) * CD + n]);
        } else if (mat == 3) {
            WaT[oo] = f2b(Wa[(t * CD + k) * CD + n]);
        } else {
            int h = n >> 4, j = n & 15;
            const float* W = (mat == 1) ? Wk : Wv;
            const float* A = (mat == 1) ? Aatt : Amsg;
            const float* wrow = W + (t * CD + k) * CD + h * 16;
            const float* acol = A + ((t * NH + h) * 16) * 16 + j;
            float s = 0.f;
#pragma unroll
            for (int d = 0; d < 16; ++d) s += wrow[d] * acol[d * 16];
            ((mat == 1) ? WkT : WvT)[oo] = f2b(s);
        }
    } else {
        int o2 = idx - 4 * WCNT;
        if (o2 < 2 * NT * CD) {
            int which = (o2 >= NT * CD) ? 1 : 0;
            int o = o2 - which * NT * CD;
            const float* B = which ? bv : bk;
            const float* A = which ? Amsg : Aatt;
            int t = o >> 7; int c = o & 127; int h = c >> 4; int j = c & 15;
            const float* brow = B + t * CD + h * 16;
            const float* acol = A + ((t * NH + h) * 16) * 16 + j;
            float s = 0.f;
#pragma unroll
            for (int d = 0; d < 16; ++d) s += brow[d] * acol[d * 16];
            (which ? bvf : bkf)[o] = s;
        }
    }
}

// block 0: exclusive prefix over NN degree bins
// block 1: vectorized 8-bucket scans over epart/npart; writes ectr/nctr tables
__launch_bounds__(1024)
__global__ void scan_all(const int* __restrict__ deg, int* __restrict__ dbase,
                         int* __restrict__ epart, int* __restrict__ npart,
                         int* __restrict__ ectr, int* __restrict__ nctr) {
    const int t = threadIdx.x;
    if (blockIdx.x == 0) {
        __shared__ int part[1024];
        int local[32];
        int s = 0;
#pragma unroll
        for (int i = 0; i < 32; ++i) { local[i] = s; s += deg[t * 32 + i]; }
        part[t] = s;
        __syncthreads();
        for (int off = 1; off < 1024; off <<= 1) {
            int v = (t >= off) ? part[t - off] : 0;
            __syncthreads();
            part[t] += v;
            __syncthreads();
        }
        int base = (t == 0) ? 0 : part[t - 1];
#pragma unroll
        for (int i = 0; i < 32; ++i) dbase[t * 32 + i] = base + local[i];
        return;
    }
    __shared__ int sc[1024 * 8];   // 32 KB
    int v[8], orig[8];
#pragma unroll
    for (int u = 0; u < 8; ++u) { orig[u] = v[u] = epart[t * 8 + u]; sc[t * 8 + u] = v[u]; }
    for (int off = 1; off < 1024; off <<= 1) {
        __syncthreads();
        int wv[8];
        bool p = (t >= off);
        if (p) {
#pragma unroll
            for (int u = 0; u < 8; ++u) wv[u] = sc[(t - off) * 8 + u];
        }
        __syncthreads();
        if (p) {
#pragma unroll
            for (int u = 0; u < 8; ++u) { v[u] += wv[u]; sc[t * 8 + u] = v[u]; }
        }
    }
    __syncthreads();
    int tot[8], base[8];
    {
        int acc = 0;
#pragma unroll
        for (int u = 0; u < 8; ++u) { tot[u] = sc[1023 * 8 + u]; base[u] = acc; acc += tot[u]; }
    }
#pragma unroll
    for (int u = 0; u < 8; ++u) epart[t * 8 + u] = base[u] + v[u] - orig[u];
    if (t == 0) {
        ectr[8] = 0; ectr[17] = 0;
        int acc = 0, ptb = 0;
        for (int u = 0; u < 8; ++u) {
            acc += tot[u]; ectr[9 + u] = acc;
            ptb += (tot[u] + 63) >> 6; ectr[18 + u] = ptb;
        }
    }
    __syncthreads();
    int nv[8], nor[8];
#pragma unroll
    for (int u = 0; u < 8; ++u) {
        nor[u] = nv[u] = (t < 128) ? npart[t * 8 + u] : 0;
        sc[t * 8 + u] = nv[u];
    }
    for (int off = 1; off < 128; off <<= 1) {
        __syncthreads();
        int wv[8];
        bool p = (t >= off && t < 128);
        if (p) {
#pragma unroll
            for (int u = 0; u < 8; ++u) wv[u] = sc[(t - off) * 8 + u];
        }
        __syncthreads();
        if (p) {
#pragma unroll
            for (int u = 0; u < 8; ++u) { nv[u] += wv[u]; sc[t * 8 + u] = nv[u]; }
        }
    }
    __syncthreads();
    int ntot[8], nbase[8];
    {
        int acc = 0;
#pragma unroll
        for (int u = 0; u < 8; ++u) { ntot[u] = sc[127 * 8 + u]; nbase[u] = acc; acc += ntot[u]; }
    }
    if (t < 128) {
#pragma unroll
        for (int u = 0; u < 8; ++u) npart[t * 8 + u] = nbase[u] + nv[u] - nor[u];
    }
    if (t == 0) {
        nctr[8] = 0; nctr[17] = 0;
        int acc = 0, ptb = 0;
        for (int u = 0; u < 8; ++u) {
            acc += ntot[u]; nctr[9 + u] = acc;
            ptb += (ntot[u] + 63) >> 6; nctr[18 + u] = ptb;
        }
    }
}

// scatter via ballot ranks; edge blocks emit packed {src,dst,pos} per attr-slot
__global__ void scatter2(const int* __restrict__ ea, const int* __restrict__ tidv,
                         const int* __restrict__ srcv, const int* __restrict__ dstv,
                         const int* __restrict__ epart, const int* __restrict__ npart,
                         const int* __restrict__ dbase, int* __restrict__ dcur,
                         int4* __restrict__ epack, int* __restrict__ nperm) {
    __shared__ int wc[4][8];
    __shared__ int wo[4][8];
    const int b = blockIdx.x;
    const int tid = threadIdx.x;
    const int lane = tid & 63, w = tid >> 6;
    const bool is_e = (b < NE / 256);
    const int* lab; const int* off; int i;
    if (is_e) { lab = ea; off = epart + b * 8; i = b * 256 + tid; }
    else { lab = tidv; off = npart + (b - NE / 256) * 8; i = (b - NE / 256) * 256 + tid; }
    int t = lab[i];
    const ull below = (1ull << lane) - 1;
    int myrank = 0;
#pragma unroll
    for (int u = 0; u < 8; ++u) {
        ull m = __ballot(t == u);
        if (lane == 0) wc[w][u] = __popcll(m);
        if (t == u) myrank = __popcll(m & below);
    }
    __syncthreads();
    if (tid < 32) {
        int u = tid & 7, w2 = tid >> 3;
        int s = 0;
        for (int w3 = 0; w3 < w2; ++w3) s += wc[w3][u];
        wo[w2][u] = s;
    }
    __syncthreads();
    int slot = off[t] + wo[w][t] + myrank;
    if (is_e) {
        int s = srcv[i], d = dstv[i];
        int pos = dbase[d] + atomicAdd(&dcur[d], 1);
        epack[slot] = int4{s, d, pos, 0};
    } else {
        nperm[slot] = i;
    }
}

// 64x128x128 bf16 MFMA GEMM, A from LDS; B-fragments direct from global (L2-hot),
// double-buffered over kk (VGPR-lean, no spills).
__device__ __forceinline__ void gemm64g(const u16* __restrict__ sA,
                                        const u16* __restrict__ gW,
                                        int rh, int ch, int lx, int quad, int lane,
                                        const float* __restrict__ biasRow,
                                        f32x4 acc[2][4]) {
#pragma unroll
    for (int nt = 0; nt < 4; ++nt) {
        float bv = biasRow[ch * 64 + nt * 16 + lx];
        acc[0][nt] = f32x4{bv, bv, bv, bv};
        acc[1][nt] = f32x4{bv, bv, bv, bv};
    }
    const int m0 = rh * 32 + lx;
    const u16* wbase = gW + (ch * 4) * 2048 + lane * 8;  // ct stride 2048, kk stride 512
    bhalf8 bb[2][4];
#pragma unroll
    for (int nt = 0; nt < 4; ++nt)
        bb[0][nt] = *(const bhalf8*)(wbase + nt * 2048);
#pragma unroll
    for (int kk = 0; kk < 4; ++kk) {
        if (kk < 3) {
#pragma unroll
            for (int nt = 0; nt < 4; ++nt)
                bb[(kk + 1) & 1][nt] = *(const bhalf8*)(wbase + nt * 2048 + (kk + 1) * 512);
        }
        const int ko = kk * 32 + quad * 8;
        bhalf8 a0 = *(const bhalf8*)&sA[m0 * 136 + ko];
        bhalf8 a1 = *(const bhalf8*)&sA[(m0 + 16) * 136 + ko];
#pragma unroll
        for (int nt = 0; nt < 4; ++nt) {
            acc[0][nt] = __builtin_amdgcn_mfma_f32_16x16x32_bf16(a0, bb[kk & 1][nt], acc[0][nt], 0, 0, 0);
            acc[1][nt] = __builtin_amdgcn_mfma_f32_16x16x32_bf16(a1, bb[kk & 1][nt], acc[1][nt], 0, 0, 0);
        }
    }
}

__launch_bounds__(256, 5)
__global__ void edge_kernel(const u16* __restrict__ xb,
                            const u16* __restrict__ WqT, const float* __restrict__ bq,
                            const u16* __restrict__ WkT, const float* __restrict__ bkf,
                            const u16* __restrict__ WvT, const float* __restrict__ bvf,
                            const float* __restrict__ pri,
                            const int* __restrict__ ectr, const int4* __restrict__ epack,
                            float* __restrict__ exs, u16* __restrict__ vts) {
    __shared__ u16 sFS[64 * 136];   // fs; reused as vt staging after V GEMM
    __shared__ int sSrc[64], sDst[64], sPos[64];

    const int tid = threadIdx.x;
    const int lane = tid & 63;
    const int w = tid >> 6;
    const int lx = lane & 15;
    const int quad = lane >> 4;
    const int ch = w & 1;
    const int rh = w >> 1;
    const int b = blockIdx.x;

    int t = -1, lt = 0;
#pragma unroll
    for (int u = 0; u < NR; ++u) {
        int p0 = ectr[17 + u], p1 = ectr[18 + u];
        if (b >= p0 && b < p1) { t = u; lt = b - p0; }
    }
    if (t < 0) return;
    const int base = ectr[8 + t];
    const int sz = ectr[9 + t] - base;
    const int start = lt * 64;

    if (tid < 64) {
        int idx = start + tid;
        int4 pk = (idx < sz) ? epack[base + idx] : int4{0, 0, NE, 0};
        sSrc[tid] = pk.x;
        sDst[tid] = pk.y;
        sPos[tid] = pk.z;
    }
    __syncthreads();

    // gather fs bf16 rows -> sFS (256B each, 16 lanes/row); fd NOT staged
#pragma unroll
    for (int it = 0; it < 4; ++it) {
        int c = tid + it * 256;
        int row = c >> 4, off = (c & 15) * 8;
        *(bhalf8*)&sFS[row * 136 + off] = *(const bhalf8*)&xb[(long)sSrc[row] * CD + off];
    }

    const int m0 = rh * 32 + lx;
    const int aoff = quad * 8;

    // ---- Q GEMM: A-fragments (fd rows) direct from global, 2-deep dbuf ----
    f32x4 qa[2][4];
    {
        const u16* pa0 = xb + (long)sDst[m0] * CD + aoff;
        const u16* pa1 = xb + (long)sDst[m0 + 16] * CD + aoff;
        const u16* wbase = WqT + t * 16384 + (ch * 4) * 2048 + lane * 8;
#pragma unroll
        for (int nt = 0; nt < 4; ++nt) {
            float bv = bq[t * CD + ch * 64 + nt * 16 + lx];
            qa[0][nt] = f32x4{bv, bv, bv, bv};
            qa[1][nt] = f32x4{bv, bv, bv, bv};
        }
        bhalf8 aq0[2], aq1[2], bb[2][4];
        aq0[0] = *(const bhalf8*)pa0;
        aq1[0] = *(const bhalf8*)pa1;
#pragma unroll
        for (int nt = 0; nt < 4; ++nt)
            bb[0][nt] = *(const bhalf8*)(wbase + nt * 2048);
#pragma unroll
        for (int kk = 0; kk < 4; ++kk) {
            if (kk < 3) {
                aq0[(kk + 1) & 1] = *(const bhalf8*)(pa0 + (kk + 1) * 32);
                aq1[(kk + 1) & 1] = *(const bhalf8*)(pa1 + (kk + 1) * 32);
#pragma unroll
                for (int nt = 0; nt < 4; ++nt)
                    bb[(kk + 1) & 1][nt] = *(const bhalf8*)(wbase + nt * 2048 + (kk + 1) * 512);
            }
#pragma unroll
            for (int nt = 0; nt < 4; ++nt) {
                qa[0][nt] = __builtin_amdgcn_mfma_f32_16x16x32_bf16(aq0[kk & 1], bb[kk & 1][nt], qa[0][nt], 0, 0, 0);
                qa[1][nt] = __builtin_amdgcn_mfma_f32_16x16x32_bf16(aq1[kk & 1], bb[kk & 1][nt], qa[1][nt], 0, 0, 0);
            }
        }
    }
    __syncthreads();   // fs staged; everyone past Q

    f32x4 ka[2][4];
    gemm64g(sFS, WkT + t * 16384, rh, ch, lx, quad, lane, bkf + t * CD, ka);

    // attention: ex = exp(q.kt * pri / 4); write exs[p][ch*4..ch*4+3]
    float ex[2][4][4];
#pragma unroll
    for (int nt = 0; nt < 4; ++nt) {
        const float ph = pri[t * NH + ch * 4 + nt] * 0.25f;
#pragma unroll
        for (int mt = 0; mt < 2; ++mt) {
#pragma unroll
            for (int reg = 0; reg < 4; ++reg) {
                float p = qa[mt][nt][reg] * ka[mt][nt][reg];
                p += __shfl_xor(p, 1);
                p += __shfl_xor(p, 2);
                p += __shfl_xor(p, 4);
                p += __shfl_xor(p, 8);
                ex[mt][nt][reg] = __expf(p * ph);
            }
        }
    }
    if (lx == 0) {
#pragma unroll
        for (int mt = 0; mt < 2; ++mt)
#pragma unroll
            for (int reg = 0; reg < 4; ++reg) {
                int erow = rh * 32 + mt * 16 + quad * 4 + reg;
                float4 e4 = {ex[mt][0][reg], ex[mt][1][reg], ex[mt][2][reg], ex[mt][3][reg]};
                *(float4*)(exs + (long)sPos[erow] * 8 + ch * 4) = e4;
            }
    }

    f32x4 va[2][4];
    gemm64g(sFS, WvT + t * 16384, rh, ch, lx, quad, lane, bvf + t * CD, va);
    __syncthreads();   // all waves done reading sFS
    // park vt (bf16) into sFS, then coalesced writeout to vts[p][*]
#pragma unroll
    for (int mt = 0; mt < 2; ++mt)
#pragma unroll
        for (int reg = 0; reg < 4; ++reg) {
            int erow = rh * 32 + mt * 16 + quad * 4 + reg;
#pragma unroll
            for (int nt = 0; nt < 4; ++nt)
                sFS[erow * 136 + ch * 64 + nt * 16 + lx] = f2b(va[mt][nt][reg]);
        }
    __syncthreads();
#pragma unroll
    for (int it = 0; it < 4; ++it) {
        int c = tid + it * 256;         // 1024 chunks: 64 rows x 16
        int row = c >> 4, off = (c & 15) * 8;
        *(bhalf8*)&vts[(long)sPos[row] * 128 + off] = *(const bhalf8*)&sFS[row * 136 + off];
    }
}

__launch_bounds__(256, 4)
__global__ void node_kernel(const u16* __restrict__ xb,
                            const u16* __restrict__ WaT, const float* __restrict__ ba,
                            const float* __restrict__ skip, const float* __restrict__ gamma,
                            const float* __restrict__ beta,
                            const int* __restrict__ nctr, const int* __restrict__ nperm,
                            const int* __restrict__ dbase, const int* __restrict__ deg,
                            const float* __restrict__ exs, const u16* __restrict__ vts,
                            float* __restrict__ out) {
    __shared__ u16 sX0[64 * 136];
    __shared__ int sNode[64], sVal[64];

    const int tid = threadIdx.x;
    const int lane = tid & 63;
    const int w = tid >> 6;
    const int lx = lane & 15;
    const int quad = lane >> 4;
    const int b = blockIdx.x;

    int t = -1, lt = 0;
#pragma unroll
    for (int u = 0; u < NT; ++u) {
        int p0 = nctr[17 + u], p1 = nctr[18 + u];
        if (b >= p0 && b < p1) { t = u; lt = b - p0; }
    }
    if (t < 0) return;
    const int base = nctr[8 + t];
    const int sz = nctr[9 + t] - base;
    const int start = lt * 64;

    if (tid < 64) {
        int idx = start + tid;
        int n = (idx < sz) ? nperm[base + idx] : -1;
        sVal[tid] = (n >= 0) ? 1 : 0;
        sNode[tid] = (n >= 0) ? n : 0;
    }
    __syncthreads();

    // x0 = sum_p ex[p][h]*vt[p][c] / (den[h]*deg); 8 rows x 8 lanes,
    // lane l8 covers cols l8*16..l8*16+15 (head l8); 4-wide unroll, dual banks
    {
        const int sub = lane >> 3;
        const int l8 = lane & 7;
        for (int r2 = 0; r2 < 2; ++r2) {
            int row = w * 16 + r2 * 8 + sub;
            int n = sNode[row];
            int s = dbase[n], d = deg[n];
            const u16* vp = vts + (long)s * 128 + l8 * 16;
            const float* ep = exs + (long)s * 8 + l8;
            float aA[16], aB[16];
#pragma unroll
            for (int c = 0; c < 16; ++c) { aA[c] = 0.f; aB[c] = 0.f; }
            float sdA = 0.f, sdB = 0.f;
            int j = 0;
            for (; j + 4 <= d; j += 4) {
                bhalf8 v0a = *(const bhalf8*)(vp + (long)(j + 0) * 128);
                bhalf8 v0b = *(const bhalf8*)(vp + (long)(j + 0) * 128 + 8);
                bhalf8 v1a = *(const bhalf8*)(vp + (long)(j + 1) * 128);
                bhalf8 v1b = *(const bhalf8*)(vp + (long)(j + 1) * 128 + 8);
                bhalf8 v2a = *(const bhalf8*)(vp + (long)(j + 2) * 128);
                bhalf8 v2b = *(const bhalf8*)(vp + (long)(j + 2) * 128 + 8);
                bhalf8 v3a = *(const bhalf8*)(vp + (long)(j + 3) * 128);
                bhalf8 v3b = *(const bhalf8*)(vp + (long)(j + 3) * 128 + 8);
                float e0 = ep[(long)(j + 0) * 8];
                float e1 = ep[(long)(j + 1) * 8];
                float e2 = ep[(long)(j + 2) * 8];
                float e3 = ep[(long)(j + 3) * 8];
#pragma unroll
                for (int c = 0; c < 8; ++c) {
                    aA[c] += e0 * b2f((u16)v0a[c]) + e1 * b2f((u16)v1a[c]);
                    aA[8 + c] += e0 * b2f((u16)v0b[c]) + e1 * b2f((u16)v1b[c]);
                    aB[c] += e2 * b2f((u16)v2a[c]) + e3 * b2f((u16)v3a[c]);
                    aB[8 + c] += e2 * b2f((u16)v2b[c]) + e3 * b2f((u16)v3b[c]);
                }
                sdA += e0 + e1;
                sdB += e2 + e3;
            }
            for (; j < d; ++j) {
                bhalf8 v0a = *(const bhalf8*)(vp + (long)j * 128);
                bhalf8 v0b = *(const bhalf8*)(vp + (long)j * 128 + 8);
                float e0 = ep[(long)j * 8];
#pragma unroll
                for (int c = 0; c < 8; ++c) {
                    aA[c] += e0 * b2f((u16)v0a[c]);
                    aA[8 + c] += e0 * b2f((u16)v0b[c]);
                }
                sdA += e0;
            }
            float sden = sdA + sdB;
            float inv = (d > 0) ? 1.f / (sden * (float)d) : 0.f;
            bhalf8 p0, p1;
#pragma unroll
            for (int c = 0; c < 8; ++c) {
                p0[c] = (short)f2b((aA[c] + aB[c]) * inv);
                p1[c] = (short)f2b((aA[8 + c] + aB[8 + c]) * inv);
            }
            *(bhalf8*)&sX0[row * 136 + l8 * 16] = p0;
            *(bhalf8*)&sX0[row * 136 + l8 * 16 + 8] = p1;
        }
    }
    __syncthreads();

    // wave w: rows 16w..16w+15, all 8 col-tiles; B-frags direct from global
    f32x4 acc[8];
#pragma unroll
    for (int nt = 0; nt < 8; ++nt) {
        float bv = ba[t * CD + nt * 16 + lx];
        acc[nt] = f32x4{bv, bv, bv, bv};
    }
    const int m0 = w * 16 + lx;
    const u16* wbase = WaT + t * 16384 + lane * 8;
#pragma unroll
    for (int kk = 0; kk < 4; ++kk) {
        bhalf8 nb[8];
#pragma unroll
        for (int ct = 0; ct < 8; ++ct)
            nb[ct] = *(const bhalf8*)(wbase + ct * 2048 + kk * 512);
        bhalf8 a = *(const bhalf8*)&sX0[m0 * 136 + kk * 32 + quad * 8];
#pragma unroll
        for (int ct = 0; ct < 8; ++ct)
            acc[ct] = __builtin_amdgcn_mfma_f32_16x16x32_bf16(a, nb[ct], acc[ct], 0, 0, 0);
    }

    const float alpha = 1.f / (1.f + __expf(-skip[t]));
    const float oma = 1.f - alpha;
    float g[8], be[8];
#pragma unroll
    for (int nt = 0; nt < 8; ++nt) {
        g[nt] = gamma[t * CD + nt * 16 + lx];
        be[nt] = beta[t * CD + nt * 16 + lx];
    }
#pragma unroll
    for (int reg = 0; reg < 4; ++reg) {
        int erow = w * 16 + quad * 4 + reg;
        int n = sNode[erow];
        const u16* xr = xb + (long)n * CD;
        float o[8];
        float s1 = 0.f, s2 = 0.f;
#pragma unroll
        for (int nt = 0; nt < 8; ++nt) {
            float xv = b2f(xr[nt * 16 + lx]);
            float ov = acc[nt][reg] * alpha + xv * oma;
            o[nt] = ov;
            s1 += ov;
            s2 += ov * ov;
        }
#pragma unroll
        for (int m = 1; m < 16; m <<= 1) {
            s1 += __shfl_xor(s1, m);
            s2 += __shfl_xor(s2, m);
        }
        float mu = s1 * (1.f / 128.f);
        float var = s2 * (1.f / 128.f) - mu * mu;
        float rs = rsqrtf(var + 1e-5f);
        if (sVal[erow]) {
            float* op = out + (long)n * CD;
#pragma unroll
            for (int nt = 0; nt < 8; ++nt)
                __builtin_nontemporal_store((o[nt] - mu) * rs * g[nt] + be[nt],
                                            &op[nt * 16 + lx]);
        }
    }
}

extern "C" void kernel_launch(void* const* d_in, const int* in_sizes, int n_in,
                              void* d_out, int out_size, void* d_ws, size_t ws_size,
                              hipStream_t stream) {
    const float* x        = (const float*)d_in[0];
    const int*   type_id  = (const int*)d_in[1];
    const int*   edge_idx = (const int*)d_in[2];
    const int*   edge_attr= (const int*)d_in[3];
    const float* Wk   = (const float*)d_in[4];
    const float* bk   = (const float*)d_in[5];
    const float* Wq   = (const float*)d_in[6];
    const float* bq   = (const float*)d_in[7];
    const float* Wv   = (const float*)d_in[8];
    const float* bv   = (const float*)d_in[9];
    const float* Wa   = (const float*)d_in[10];
    const float* ba   = (const float*)d_in[11];
    const float* pri  = (const float*)d_in[12];
    const float* Aatt = (const float*)d_in[13];
    const float* Amsg = (const float*)d_in[14];
    const float* skip = (const float*)d_in[15];
    const float* gam  = (const float*)d_in[16];
    const float* bet  = (const float*)d_in[17];

    char* ws = (char*)d_ws;
    u16*   WqT  = (u16*)(ws + 0);
    u16*   WkT  = (u16*)(ws + 262144);
    u16*   WvT  = (u16*)(ws + 524288);
    u16*   WaT  = (u16*)(ws + 786432);
    float* bkf  = (float*)(ws + 1048576);
    float* bvf  = (float*)(ws + 1052672);
    float* exs  = (float*)(ws + 1056768);
    u16*   vts  = (u16*)(ws + 9447424);
    int*   deg  = (int*)  (ws + 76572672);
    int*   dcur = (int*)  (ws + 76703744);
    int*   dbase= (int*)  (ws + 76834816);
    int*   nperm= (int*)  (ws + 78014464);
    int*   ectr = (int*)  (ws + 78145536);
    int*   nctr = (int*)  (ws + 78145792);
    int*   epart= (int*)  (ws + 78146048);
    int*   npart= (int*)  (ws + 78178816);
    u16*   xb   = (u16*)  (ws + 78182912);
    int4*  epack= (int4*) (ws + 86571520);

    const int* src = edge_idx;
    const int* dst = edge_idx + NE;

    hipMemsetAsync(deg, 0, 2 * NN * sizeof(int), stream);   // deg + dcur
    prep_all<<<PREP_BLOCKS + XB_BLOCKS + HIST_BLOCKS, 256, 0, stream>>>(
        Wk, bk, Wq, Wv, bv, Wa, Aatt, Amsg, x, edge_attr, type_id, dst,
        WqT, WkT, WvT, WaT, bkf, bvf, xb, epart, npart, deg);
    scan_all<<<2, 1024, 0, stream>>>(deg, dbase, epart, npart, ectr, nctr);
    scatter2<<<NE / 256 + NN / 256, 256, 0, stream>>>(edge_attr, type_id, src, dst,
                                                      epart, npart, dbase, dcur,
                                                      epack, nperm);
    edge_kernel<<<NE / 64 + NR, 256, 0, stream>>>(xb, WqT, bq, WkT, bkf, WvT, bvf,
                                                  pri, ectr, epack, exs, vts);
    node_kernel<<<NN / 64 + NT, 256, 0, stream>>>(xb, WaT, ba, skip, gam, bet, nctr, nperm,
                                                  dbase, deg, exs, vts, (float*)d_out);
}

// Round 11
// 227.938 us; speedup vs baseline: 1.3454x; 1.3454x over previous
//
#include <hip/hip_runtime.h>
#include <math.h>

#define NN 32768
#define NE 262144
#define CD 128
#define NH 8
#define NT 8
#define NR 8

typedef unsigned short u16;
typedef unsigned long long ull;
typedef __attribute__((ext_vector_type(8))) short bhalf8;
typedef __attribute__((ext_vector_type(4))) float f32x4;

// ---------------- workspace layout (bytes) ----------------
// WqT  @ 0         262144   bf16, MFMA-fragment order [t][ct][kk][quad][lx][8]
// WkT  @ 262144    262144   (fused rel_att)
// WvT  @ 524288    262144   (fused rel_msg)
// WaT  @ 786432    262144
// bkf  @ 1048576   4096     fp32 fused bias
// bvf  @ 1052672   4096
// exs  @ 1056768   (NE+64)*8*4  = 8390656
// vts  @ 9447424   (NE+64)*128*2 = 67125248
// deg  @ 76572672  NN*4
// dcur @ 76703744  NN*4   (adjacent: one memset covers deg+dcur)
// dbase@ 76834816  NN*4
// nperm@ 78014464  NN*4
// ectr @ 78145536  64 ints
// nctr @ 78145792  64 ints
// epart@ 78146048  1024*8 ints = 32768
// npart@ 78178816  128*8 ints  = 4096
// xb   @ 78182912  NN*CD*2 = 8388608   (bf16 x)
// epack@ 86571520  NE*16 = 4194304     (int4 {src,dst,pos,pad} per attr-slot)

__device__ __forceinline__ u16 f2b(float f) {
    union { float f; unsigned u; } v; v.f = f;
    unsigned r = v.u + 0x7FFF + ((v.u >> 16) & 1);
    return (u16)(r >> 16);
}
__device__ __forceinline__ float b2f(unsigned h) {
    union { unsigned u; float f; } v; v.u = h << 16;
    return v.f;
}

#define PREP_BLOCKS 2057
#define XB_BLOCKS 2048
#define HIST_BLOCKS 1024

// weights prep (0..2056) + x->bf16 (2057..4104) + hists (4105..5128)
// deg/dcur zeroed by hipMemsetAsync before this launch.
__global__ void prep_all(const float* __restrict__ Wk, const float* __restrict__ bk,
                         const float* __restrict__ Wq,
                         const float* __restrict__ Wv, const float* __restrict__ bv,
                         const float* __restrict__ Wa,
                         const float* __restrict__ Aatt, const float* __restrict__ Amsg,
                         const float* __restrict__ x,
                         const int* __restrict__ ea, const int* __restrict__ tidv,
                         const int* __restrict__ dstv,
                         u16* __restrict__ WqT, u16* __restrict__ WkT,
                         u16* __restrict__ WvT, u16* __restrict__ WaT,
                         float* __restrict__ bkf, float* __restrict__ bvf,
                         u16* __restrict__ xb,
                         int* __restrict__ epart, int* __restrict__ npart,
                         int* __restrict__ deg) {
    const int bx = blockIdx.x;
    if (bx >= PREP_BLOCKS + XB_BLOCKS) {
        // ---- histograms ----
        __shared__ int wc[4][8];
        const int hb = bx - PREP_BLOCKS - XB_BLOCKS;
        const int tid = threadIdx.x;
        const int lane = tid & 63, w = tid >> 6;
        int i = hb * 256 + tid;
        int t = ea[i];
        atomicAdd(&deg[dstv[i]], 1);
#pragma unroll
        for (int u = 0; u < 8; ++u) {
            ull m = __ballot(t == u);
            if (lane == 0) wc[w][u] = __popcll(m);
        }
        __syncthreads();
        if (tid < 8) epart[hb * 8 + tid] = wc[0][tid] + wc[1][tid] + wc[2][tid] + wc[3][tid];
        if (hb < NN / 256) {
            int tn = tidv[i];
            __syncthreads();
#pragma unroll
            for (int u = 0; u < 8; ++u) {
                ull m = __ballot(tn == u);
                if (lane == 0) wc[w][u] = __popcll(m);
            }
            __syncthreads();
            if (tid < 8) npart[hb * 8 + tid] = wc[0][tid] + wc[1][tid] + wc[2][tid] + wc[3][tid];
        }
        return;
    }
    if (bx >= PREP_BLOCKS) {
        int zi = (bx - PREP_BLOCKS) * 256 + threadIdx.x;
        long basei = (long)zi * 8;
        float4 v0 = *(const float4*)(x + basei);
        float4 v1 = *(const float4*)(x + basei + 4);
        bhalf8 pk;
        pk[0] = (short)f2b(v0.x); pk[1] = (short)f2b(v0.y);
        pk[2] = (short)f2b(v0.z); pk[3] = (short)f2b(v0.w);
        pk[4] = (short)f2b(v1.x); pk[5] = (short)f2b(v1.y);
        pk[6] = (short)f2b(v1.z); pk[7] = (short)f2b(v1.w);
        *(bhalf8*)(xb + basei) = pk;
        return;
    }
    const int WCNT = NT * CD * CD;  // 131072 per matrix
    int idx = bx * 256 + threadIdx.x;
    if (idx < 4 * WCNT) {
        int mat = idx >> 17;
        int o = idx & (WCNT - 1);
        int t = o >> 14;
        int n = (o >> 7) & 127;
        int k = o & 127;
        int ct = n >> 4, lx2 = n & 15, kk = k >> 5, qd = (k >> 3) & 3, dd = k & 7;
        int oo = t * 16384 + (((ct * 4 + kk) * 4 + qd) * 16 + lx2) * 8 + dd;
        if (mat == 0) {
            WqT[oo] = f2b(Wq[(t * CD + k) * CD + n]);
        } else if (mat == 3) {
            WaT[oo] = f2b(Wa[(t * CD + k) * CD + n]);
        } else {
            int h = n >> 4, j = n & 15;
            const float* W = (mat == 1) ? Wk : Wv;
            const float* A = (mat == 1) ? Aatt : Amsg;
            const float* wrow = W + (t * CD + k) * CD + h * 16;
            const float* acol = A + ((t * NH + h) * 16) * 16 + j;
            float s = 0.f;
#pragma unroll
            for (int d = 0; d < 16; ++d) s += wrow[d] * acol[d * 16];
            ((mat == 1) ? WkT : WvT)[oo] = f2b(s);
        }
    } else {
        int o2 = idx - 4 * WCNT;
        if (o2 < 2 * NT * CD) {
            int which = (o2 >= NT * CD) ? 1 : 0;
            int o = o2 - which * NT * CD;
            const float* B = which ? bv : bk;
            const float* A = which ? Amsg : Aatt;
            int t = o >> 7; int c = o & 127; int h = c >> 4; int j = c & 15;
            const float* brow = B + t * CD + h * 16;
            const float* acol = A + ((t * NH + h) * 16) * 16 + j;
            float s = 0.f;
#pragma unroll
            for (int d = 0; d < 16; ++d) s += brow[d] * acol[d * 16];
            (which ? bvf : bkf)[o] = s;
        }
    }
}

// block 0: exclusive prefix over NN degree bins
// block 1: vectorized 8-bucket scans over epart/npart; writes ectr/nctr tables
__launch_bounds__(1024)
__global__ void scan_all(const int* __restrict__ deg, int* __restrict__ dbase,
                         int* __restrict__ epart, int* __restrict__ npart,
                         int* __restrict__ ectr, int* __restrict__ nctr) {
    const int t = threadIdx.x;
    if (blockIdx.x == 0) {
        __shared__ int part[1024];
        int local[32];
        int s = 0;
#pragma unroll
        for (int i = 0; i < 32; ++i) { local[i] = s; s += deg[t * 32 + i]; }
        part[t] = s;
        __syncthreads();
        for (int off = 1; off < 1024; off <<= 1) {
            int v = (t >= off) ? part[t - off] : 0;
            __syncthreads();
            part[t] += v;
            __syncthreads();
        }
        int base = (t == 0) ? 0 : part[t - 1];
#pragma unroll
        for (int i = 0; i < 32; ++i) dbase[t * 32 + i] = base + local[i];
        return;
    }
    __shared__ int sc[1024 * 8];   // 32 KB
    int v[8], orig[8];
#pragma unroll
    for (int u = 0; u < 8; ++u) { orig[u] = v[u] = epart[t * 8 + u]; sc[t * 8 + u] = v[u]; }
    for (int off = 1; off < 1024; off <<= 1) {
        __syncthreads();
        int wv[8];
        bool p = (t >= off);
        if (p) {
#pragma unroll
            for (int u = 0; u < 8; ++u) wv[u] = sc[(t - off) * 8 + u];
        }
        __syncthreads();
        if (p) {
#pragma unroll
            for (int u = 0; u < 8; ++u) { v[u] += wv[u]; sc[t * 8 + u] = v[u]; }
        }
    }
    __syncthreads();
    int tot[8], base[8];
    {
        int acc = 0;
#pragma unroll
        for (int u = 0; u < 8; ++u) { tot[u] = sc[1023 * 8 + u]; base[u] = acc; acc += tot[u]; }
    }
#pragma unroll
    for (int u = 0; u < 8; ++u) epart[t * 8 + u] = base[u] + v[u] - orig[u];
    if (t == 0) {
        ectr[8] = 0; ectr[17] = 0;
        int acc = 0, ptb = 0;
        for (int u = 0; u < 8; ++u) {
            acc += tot[u]; ectr[9 + u] = acc;
            ptb += (tot[u] + 63) >> 6; ectr[18 + u] = ptb;
        }
    }
    __syncthreads();
    int nv[8], nor[8];
#pragma unroll
    for (int u = 0; u < 8; ++u) {
        nor[u] = nv[u] = (t < 128) ? npart[t * 8 + u] : 0;
        sc[t * 8 + u] = nv[u];
    }
    for (int off = 1; off < 128; off <<= 1) {
        __syncthreads();
        int wv[8];
        bool p = (t >= off && t < 128);
        if (p) {
#pragma unroll
            for (int u = 0; u < 8; ++u) wv[u] = sc[(t - off) * 8 + u];
        }
        __syncthreads();
        if (p) {
#pragma unroll
            for (int u = 0; u < 8; ++u) { nv[u] += wv[u]; sc[t * 8 + u] = nv[u]; }
        }
    }
    __syncthreads();
    int ntot[8], nbase[8];
    {
        int acc = 0;
#pragma unroll
        for (int u = 0; u < 8; ++u) { ntot[u] = sc[127 * 8 + u]; nbase[u] = acc; acc += ntot[u]; }
    }
    if (t < 128) {
#pragma unroll
        for (int u = 0; u < 8; ++u) npart[t * 8 + u] = nbase[u] + nv[u] - nor[u];
    }
    if (t == 0) {
        nctr[8] = 0; nctr[17] = 0;
        int acc = 0, ptb = 0;
        for (int u = 0; u < 8; ++u) {
            acc += ntot[u]; nctr[9 + u] = acc;
            ptb += (ntot[u] + 63) >> 6; nctr[18 + u] = ptb;
        }
    }
}

// scatter via ballot ranks; edge blocks emit packed {src,dst,pos} per attr-slot
__global__ void scatter2(const int* __restrict__ ea, const int* __restrict__ tidv,
                         const int* __restrict__ srcv, const int* __restrict__ dstv,
                         const int* __restrict__ epart, const int* __restrict__ npart,
                         const int* __restrict__ dbase, int* __restrict__ dcur,
                         int4* __restrict__ epack, int* __restrict__ nperm) {
    __shared__ int wc[4][8];
    __shared__ int wo[4][8];
    const int b = blockIdx.x;
    const int tid = threadIdx.x;
    const int lane = tid & 63, w = tid >> 6;
    const bool is_e = (b < NE / 256);
    const int* lab; const int* off; int i;
    if (is_e) { lab = ea; off = epart + b * 8; i = b * 256 + tid; }
    else { lab = tidv; off = npart + (b - NE / 256) * 8; i = (b - NE / 256) * 256 + tid; }
    int t = lab[i];
    const ull below = (1ull << lane) - 1;
    int myrank = 0;
#pragma unroll
    for (int u = 0; u < 8; ++u) {
        ull m = __ballot(t == u);
        if (lane == 0) wc[w][u] = __popcll(m);
        if (t == u) myrank = __popcll(m & below);
    }
    __syncthreads();
    if (tid < 32) {
        int u = tid & 7, w2 = tid >> 3;
        int s = 0;
        for (int w3 = 0; w3 < w2; ++w3) s += wc[w3][u];
        wo[w2][u] = s;
    }
    __syncthreads();
    int slot = off[t] + wo[w][t] + myrank;
    if (is_e) {
        int s = srcv[i], d = dstv[i];
        int pos = dbase[d] + atomicAdd(&dcur[d], 1);
        epack[slot] = int4{s, d, pos, 0};
    } else {
        nperm[slot] = i;
    }
}

// 64x128x128 bf16 MFMA GEMM, A from LDS, B direct from global (L2-hot),
// 3-deep rolling prefetch over kk; first 3 tiers optionally preloaded.
__device__ __forceinline__ void gemm64g3(const u16* __restrict__ sA,
                                         const u16* __restrict__ wbase,
                                         const bhalf8 pre[3][4], bool usePre,
                                         int rh, int ch, int lx, int quad,
                                         const float* __restrict__ biasRow,
                                         f32x4 acc[2][4]) {
#pragma unroll
    for (int nt = 0; nt < 4; ++nt) {
        float bv = biasRow[ch * 64 + nt * 16 + lx];
        acc[0][nt] = f32x4{bv, bv, bv, bv};
        acc[1][nt] = f32x4{bv, bv, bv, bv};
    }
    const int m0 = rh * 32 + lx;
    bhalf8 bb[3][4];
    if (usePre) {
#pragma unroll
        for (int s = 0; s < 3; ++s)
#pragma unroll
            for (int nt = 0; nt < 4; ++nt) bb[s][nt] = pre[s][nt];
    } else {
#pragma unroll
        for (int s = 0; s < 3; ++s)
#pragma unroll
            for (int nt = 0; nt < 4; ++nt)
                bb[s][nt] = *(const bhalf8*)(wbase + nt * 2048 + s * 512);
    }
#pragma unroll
    for (int kk = 0; kk < 4; ++kk) {
        const int ko = kk * 32 + quad * 8;
        bhalf8 a0 = *(const bhalf8*)&sA[m0 * 136 + ko];
        bhalf8 a1 = *(const bhalf8*)&sA[(m0 + 16) * 136 + ko];
#pragma unroll
        for (int nt = 0; nt < 4; ++nt) {
            acc[0][nt] = __builtin_amdgcn_mfma_f32_16x16x32_bf16(a0, bb[kk % 3][nt], acc[0][nt], 0, 0, 0);
            acc[1][nt] = __builtin_amdgcn_mfma_f32_16x16x32_bf16(a1, bb[kk % 3][nt], acc[1][nt], 0, 0, 0);
        }
        if (kk == 0) {
#pragma unroll
            for (int nt = 0; nt < 4; ++nt)
                bb[0][nt] = *(const bhalf8*)(wbase + nt * 2048 + 3 * 512);
        }
    }
}

// 2-deep variant (lower register pressure; used for V where ex[] is live)
__device__ __forceinline__ void gemm64g(const u16* __restrict__ sA,
                                        const u16* __restrict__ wbase,
                                        int rh, int ch, int lx, int quad,
                                        const float* __restrict__ biasRow,
                                        f32x4 acc[2][4]) {
#pragma unroll
    for (int nt = 0; nt < 4; ++nt) {
        float bv = biasRow[ch * 64 + nt * 16 + lx];
        acc[0][nt] = f32x4{bv, bv, bv, bv};
        acc[1][nt] = f32x4{bv, bv, bv, bv};
    }
    const int m0 = rh * 32 + lx;
    bhalf8 bb[2][4];
#pragma unroll
    for (int nt = 0; nt < 4; ++nt)
        bb[0][nt] = *(const bhalf8*)(wbase + nt * 2048);
#pragma unroll
    for (int kk = 0; kk < 4; ++kk) {
        if (kk < 3) {
#pragma unroll
            for (int nt = 0; nt < 4; ++nt)
                bb[(kk + 1) & 1][nt] = *(const bhalf8*)(wbase + nt * 2048 + (kk + 1) * 512);
        }
        const int ko = kk * 32 + quad * 8;
        bhalf8 a0 = *(const bhalf8*)&sA[m0 * 136 + ko];
        bhalf8 a1 = *(const bhalf8*)&sA[(m0 + 16) * 136 + ko];
#pragma unroll
        for (int nt = 0; nt < 4; ++nt) {
            acc[0][nt] = __builtin_amdgcn_mfma_f32_16x16x32_bf16(a0, bb[kk & 1][nt], acc[0][nt], 0, 0, 0);
            acc[1][nt] = __builtin_amdgcn_mfma_f32_16x16x32_bf16(a1, bb[kk & 1][nt], acc[1][nt], 0, 0, 0);
        }
    }
}

__launch_bounds__(256, 4)
__global__ void edge_kernel(const u16* __restrict__ xb,
                            const u16* __restrict__ WqT, const float* __restrict__ bq,
                            const u16* __restrict__ WkT, const float* __restrict__ bkf,
                            const u16* __restrict__ WvT, const float* __restrict__ bvf,
                            const float* __restrict__ pri,
                            const int* __restrict__ ectr, const int4* __restrict__ epack,
                            float* __restrict__ exs, u16* __restrict__ vts) {
    __shared__ u16 sFS[64 * 136];
    __shared__ u16 sFD[64 * 136];   // fd; later reused as vt staging
    __shared__ int sSrc[64], sDst[64], sPos[64];

    const int tid = threadIdx.x;
    const int lane = tid & 63;
    const int w = tid >> 6;
    const int lx = lane & 15;
    const int quad = lane >> 4;
    const int ch = w & 1;
    const int rh = w >> 1;
    const int b = blockIdx.x;

    int t = -1, lt = 0;
#pragma unroll
    for (int u = 0; u < NR; ++u) {
        int p0 = ectr[17 + u], p1 = ectr[18 + u];
        if (b >= p0 && b < p1) { t = u; lt = b - p0; }
    }
    if (t < 0) return;
    const int base = ectr[8 + t];
    const int sz = ectr[9 + t] - base;
    const int start = lt * 64;

    const u16* wqb = WqT + t * 16384 + (ch * 4) * 2048 + lane * 8;
    const u16* wkb = WkT + t * 16384 + (ch * 4) * 2048 + lane * 8;
    const u16* wvb = WvT + t * 16384 + (ch * 4) * 2048 + lane * 8;

    // pre-issue Q's first 3 kk-tiers of B-fragments (independent of LDS);
    // they complete during the gather + barrier drain
    bhalf8 qpre[3][4];
#pragma unroll
    for (int s = 0; s < 3; ++s)
#pragma unroll
        for (int nt = 0; nt < 4; ++nt)
            qpre[s][nt] = *(const bhalf8*)(wqb + nt * 2048 + s * 512);

    if (tid < 64) {
        int idx = start + tid;
        int4 pk = (idx < sz) ? epack[base + idx] : int4{0, 0, NE, 0};
        sSrc[tid] = pk.x;
        sDst[tid] = pk.y;
        sPos[tid] = pk.z;
    }
    __syncthreads();

    // gather fs/fd bf16 rows (256B each, 16 lanes/row)
#pragma unroll
    for (int it = 0; it < 4; ++it) {
        int c = tid + it * 256;
        int row = c >> 4, off = (c & 15) * 8;
        *(bhalf8*)&sFS[row * 136 + off] = *(const bhalf8*)&xb[(long)sSrc[row] * CD + off];
        *(bhalf8*)&sFD[row * 136 + off] = *(const bhalf8*)&xb[(long)sDst[row] * CD + off];
    }
    __syncthreads();

    f32x4 qa[2][4], ka[2][4];
    gemm64g3(sFD, wqb, qpre, true, rh, ch, lx, quad, bq + t * CD, qa);
    gemm64g3(sFS, wkb, qpre, false, rh, ch, lx, quad, bkf + t * CD, ka);

    // attention: ex = exp(q.kt * pri / 4); write exs[p][ch*4..ch*4+3]
    float ex[2][4][4];
#pragma unroll
    for (int nt = 0; nt < 4; ++nt) {
        const float ph = pri[t * NH + ch * 4 + nt] * 0.25f;
#pragma unroll
        for (int mt = 0; mt < 2; ++mt) {
#pragma unroll
            for (int reg = 0; reg < 4; ++reg) {
                float p = qa[mt][nt][reg] * ka[mt][nt][reg];
                p += __shfl_xor(p, 1);
                p += __shfl_xor(p, 2);
                p += __shfl_xor(p, 4);
                p += __shfl_xor(p, 8);
                ex[mt][nt][reg] = __expf(p * ph);
            }
        }
    }
    if (lx == 0) {
#pragma unroll
        for (int mt = 0; mt < 2; ++mt)
#pragma unroll
            for (int reg = 0; reg < 4; ++reg) {
                int erow = rh * 32 + mt * 16 + quad * 4 + reg;
                float4 e4 = {ex[mt][0][reg], ex[mt][1][reg], ex[mt][2][reg], ex[mt][3][reg]};
                *(float4*)(exs + (long)sPos[erow] * 8 + ch * 4) = e4;
            }
    }

    f32x4 va[2][4];
    gemm64g(sFS, wvb, rh, ch, lx, quad, bvf + t * CD, va);
    __syncthreads();
    // park vt (bf16) into sFD, then coalesced writeout to vts[p][*]
#pragma unroll
    for (int mt = 0; mt < 2; ++mt)
#pragma unroll
        for (int reg = 0; reg < 4; ++reg) {
            int erow = rh * 32 + mt * 16 + quad * 4 + reg;
#pragma unroll
            for (int nt = 0; nt < 4; ++nt)
                sFD[erow * 136 + ch * 64 + nt * 16 + lx] = f2b(va[mt][nt][reg]);
        }
    __syncthreads();
#pragma unroll
    for (int it = 0; it < 4; ++it) {
        int c = tid + it * 256;         // 1024 chunks: 64 rows x 16
        int row = c >> 4, off = (c & 15) * 8;
        *(bhalf8*)&vts[(long)sPos[row] * 128 + off] = *(const bhalf8*)&sFD[row * 136 + off];
    }
}

__launch_bounds__(256, 4)
__global__ void node_kernel(const u16* __restrict__ xb,
                            const u16* __restrict__ WaT, const float* __restrict__ ba,
                            const float* __restrict__ skip, const float* __restrict__ gamma,
                            const float* __restrict__ beta,
                            const int* __restrict__ nctr, const int* __restrict__ nperm,
                            const int* __restrict__ dbase, const int* __restrict__ deg,
                            const float* __restrict__ exs, const u16* __restrict__ vts,
                            float* __restrict__ out) {
    __shared__ u16 sX0[64 * 136];
    __shared__ int sNode[64], sVal[64];

    const int tid = threadIdx.x;
    const int lane = tid & 63;
    const int w = tid >> 6;
    const int lx = lane & 15;
    const int quad = lane >> 4;
    const int b = blockIdx.x;

    int t = -1, lt = 0;
#pragma unroll
    for (int u = 0; u < NT; ++u) {
        int p0 = nctr[17 + u], p1 = nctr[18 + u];
        if (b >= p0 && b < p1) { t = u; lt = b - p0; }
    }
    if (t < 0) return;
    const int base = nctr[8 + t];
    const int sz = nctr[9 + t] - base;
    const int start = lt * 64;

    if (tid < 64) {
        int idx = start + tid;
        int n = (idx < sz) ? nperm[base + idx] : -1;
        sVal[tid] = (n >= 0) ? 1 : 0;
        sNode[tid] = (n >= 0) ? n : 0;
    }
    __syncthreads();

    // x0 = sum_p ex[p][h]*vt[p][c] / (den[h]*deg); 8 rows x 8 lanes,
    // lane l8 covers cols l8*16..l8*16+15 (head l8); 4-wide unroll, dual banks
    {
        const int sub = lane >> 3;
        const int l8 = lane & 7;
        for (int r2 = 0; r2 < 2; ++r2) {
            int row = w * 16 + r2 * 8 + sub;
            int n = sNode[row];
            int s = dbase[n], d = deg[n];
            const u16* vp = vts + (long)s * 128 + l8 * 16;
            const float* ep = exs + (long)s * 8 + l8;
            float aA[16], aB[16];
#pragma unroll
            for (int c = 0; c < 16; ++c) { aA[c] = 0.f; aB[c] = 0.f; }
            float sdA = 0.f, sdB = 0.f;
            int j = 0;
            for (; j + 4 <= d; j += 4) {
                bhalf8 v0a = *(const bhalf8*)(vp + (long)(j + 0) * 128);
                bhalf8 v0b = *(const bhalf8*)(vp + (long)(j + 0) * 128 + 8);
                bhalf8 v1a = *(const bhalf8*)(vp + (long)(j + 1) * 128);
                bhalf8 v1b = *(const bhalf8*)(vp + (long)(j + 1) * 128 + 8);
                bhalf8 v2a = *(const bhalf8*)(vp + (long)(j + 2) * 128);
                bhalf8 v2b = *(const bhalf8*)(vp + (long)(j + 2) * 128 + 8);
                bhalf8 v3a = *(const bhalf8*)(vp + (long)(j + 3) * 128);
                bhalf8 v3b = *(const bhalf8*)(vp + (long)(j + 3) * 128 + 8);
                float e0 = ep[(long)(j + 0) * 8];
                float e1 = ep[(long)(j + 1) * 8];
                float e2 = ep[(long)(j + 2) * 8];
                float e3 = ep[(long)(j + 3) * 8];
#pragma unroll
                for (int c = 0; c < 8; ++c) {
                    aA[c] += e0 * b2f((u16)v0a[c]) + e1 * b2f((u16)v1a[c]);
                    aA[8 + c] += e0 * b2f((u16)v0b[c]) + e1 * b2f((u16)v1b[c]);
                    aB[c] += e2 * b2f((u16)v2a[c]) + e3 * b2f((u16)v3a[c]);
                    aB[8 + c] += e2 * b2f((u16)v2b[c]) + e3 * b2f((u16)v3b[c]);
                }
                sdA += e0 + e1;
                sdB += e2 + e3;
            }
            for (; j < d; ++j) {
                bhalf8 v0a = *(const bhalf8*)(vp + (long)j * 128);
                bhalf8 v0b = *(const bhalf8*)(vp + (long)j * 128 + 8);
                float e0 = ep[(long)j * 8];
#pragma unroll
                for (int c = 0; c < 8; ++c) {
                    aA[c] += e0 * b2f((u16)v0a[c]);
                    aA[8 + c] += e0 * b2f((u16)v0b[c]);
                }
                sdA += e0;
            }
            float sden = sdA + sdB;
            float inv = (d > 0) ? 1.f / (sden * (float)d) : 0.f;
            bhalf8 p0, p1;
#pragma unroll
            for (int c = 0; c < 8; ++c) {
                p0[c] = (short)f2b((aA[c] + aB[c]) * inv);
                p1[c] = (short)f2b((aA[8 + c] + aB[8 + c]) * inv);
            }
            *(bhalf8*)&sX0[row * 136 + l8 * 16] = p0;
            *(bhalf8*)&sX0[row * 136 + l8 * 16 + 8] = p1;
        }
    }
    __syncthreads();

    // wave w: rows 16w..16w+15, all 8 col-tiles; B-frags direct from global
    f32x4 acc[8];
#pragma unroll
    for (int nt = 0; nt < 8; ++nt) {
        float bv = ba[t * CD + nt * 16 + lx];
        acc[nt] = f32x4{bv, bv, bv, bv};
    }
    const int m0 = w * 16 + lx;
    const u16* wbase = WaT + t * 16384 + lane * 8;
#pragma unroll
    for (int kk = 0; kk < 4; ++kk) {
        bhalf8 nb[8];
#pragma unroll
        for (int ct = 0; ct < 8; ++ct)
            nb[ct] = *(const bhalf8*)(wbase + ct * 2048 + kk * 512);
        bhalf8 a = *(const bhalf8*)&sX0[m0 * 136 + kk * 32 + quad * 8];
#pragma unroll
        for (int ct = 0; ct < 8; ++ct)
            acc[ct] = __builtin_amdgcn_mfma_f32_16x16x32_bf16(a, nb[ct], acc[ct], 0, 0, 0);
    }

    const float alpha = 1.f / (1.f + __expf(-skip[t]));
    const float oma = 1.f - alpha;
    float g[8], be[8];
#pragma unroll
    for (int nt = 0; nt < 8; ++nt) {
        g[nt] = gamma[t * CD + nt * 16 + lx];
        be[nt] = beta[t * CD + nt * 16 + lx];
    }
#pragma unroll
    for (int reg = 0; reg < 4; ++reg) {
        int erow = w * 16 + quad * 4 + reg;
        int n = sNode[erow];
        const u16* xr = xb + (long)n * CD;
        float o[8];
        float s1 = 0.f, s2 = 0.f;
#pragma unroll
        for (int nt = 0; nt < 8; ++nt) {
            float xv = b2f(xr[nt * 16 + lx]);
            float ov = acc[nt][reg] * alpha + xv * oma;
            o[nt] = ov;
            s1 += ov;
            s2 += ov * ov;
        }
#pragma unroll
        for (int m = 1; m < 16; m <<= 1) {
            s1 += __shfl_xor(s1, m);
            s2 += __shfl_xor(s2, m);
        }
        float mu = s1 * (1.f / 128.f);
        float var = s2 * (1.f / 128.f) - mu * mu;
        float rs = rsqrtf(var + 1e-5f);
        if (sVal[erow]) {
            float* op = out + (long)n * CD;
#pragma unroll
            for (int nt = 0; nt < 8; ++nt)
                __builtin_nontemporal_store((o[nt] - mu) * rs * g[nt] + be[nt],
                                            &op[nt * 16 + lx]);
        }
    }
}

extern "C" void kernel_launch(void* const* d_in, const int* in_sizes, int n_in,
                              void* d_out, int out_size, void* d_ws, size_t ws_size,
                              hipStream_t stream) {
    const float* x        = (const float*)d_in[0];
    const int*   type_id  = (const int*)d_in[1];
    const int*   edge_idx = (const int*)d_in[2];
    const int*   edge_attr= (const int*)d_in[3];
    const float* Wk   = (const float*)d_in[4];
    const float* bk   = (const float*)d_in[5];
    const float* Wq   = (const float*)d_in[6];
    const float* bq   = (const float*)d_in[7];
    const float* Wv   = (const float*)d_in[8];
    const float* bv   = (const float*)d_in[9];
    const float* Wa   = (const float*)d_in[10];
    const float* ba   = (const float*)d_in[11];
    const float* pri  = (const float*)d_in[12];
    const float* Aatt = (const float*)d_in[13];
    const float* Amsg = (const float*)d_in[14];
    const float* skip = (const float*)d_in[15];
    const float* gam  = (const float*)d_in[16];
    const float* bet  = (const float*)d_in[17];

    char* ws = (char*)d_ws;
    u16*   WqT  = (u16*)(ws + 0);
    u16*   WkT  = (u16*)(ws + 262144);
    u16*   WvT  = (u16*)(ws + 524288);
    u16*   WaT  = (u16*)(ws + 786432);
    float* bkf  = (float*)(ws + 1048576);
    float* bvf  = (float*)(ws + 1052672);
    float* exs  = (float*)(ws + 1056768);
    u16*   vts  = (u16*)(ws + 9447424);
    int*   deg  = (int*)  (ws + 76572672);
    int*   dcur = (int*)  (ws + 76703744);
    int*   dbase= (int*)  (ws + 76834816);
    int*   nperm= (int*)  (ws + 78014464);
    int*   ectr = (int*)  (ws + 78145536);
    int*   nctr = (int*)  (ws + 78145792);
    int*   epart= (int*)  (ws + 78146048);
    int*   npart= (int*)  (ws + 78178816);
    u16*   xb   = (u16*)  (ws + 78182912);
    int4*  epack= (int4*) (ws + 86571520);

    const int* src = edge_idx;
    const int* dst = edge_idx + NE;

    hipMemsetAsync(deg, 0, 2 * NN * sizeof(int), stream);   // deg + dcur
    prep_all<<<PREP_BLOCKS + XB_BLOCKS + HIST_BLOCKS, 256, 0, stream>>>(
        Wk, bk, Wq, Wv, bv, Wa, Aatt, Amsg, x, edge_attr, type_id, dst,
        WqT, WkT, WvT, WaT, bkf, bvf, xb, epart, npart, deg);
    scan_all<<<2, 1024, 0, stream>>>(deg, dbase, epart, npart, ectr, nctr);
    scatter2<<<NE / 256 + NN / 256, 256, 0, stream>>>(edge_attr, type_id, src, dst,
                                                      epart, npart, dbase, dcur,
                                                      epack, nperm);
    edge_kernel<<<NE / 64 + NR, 256, 0, stream>>>(xb, WqT, bq, WkT, bkf, WvT, bvf,
                                                  pri, ectr, epack, exs, vts);
    node_kernel<<<NN / 64 + NT, 256, 0, stream>>>(xb, WaT, ba, skip, gam, bet, nctr, nperm,
                                                  dbase, deg, exs, vts, (float*)d_out);
}